// Round 9
// baseline (751.365 us; speedup 1.0000x reference)
//
#include <hip/hip_runtime.h>

typedef __attribute__((ext_vector_type(8))) short bf16x8;
typedef __attribute__((ext_vector_type(4))) float f32x4;
typedef __attribute__((ext_vector_type(4))) unsigned u32x4;
typedef unsigned short u16;

// ---------- helpers ----------
__device__ __forceinline__ unsigned cvt_pk(float lo, float hi) {
  unsigned r;
  asm("v_cvt_pk_bf16_f32 %0, %1, %2" : "=v"(r) : "v"(lo), "v"(hi));
  return r;
}
__device__ __forceinline__ float bflo(unsigned d) { return __uint_as_float(d << 16); }
__device__ __forceinline__ float bfhi(unsigned d) { return __uint_as_float(d & 0xffff0000u); }
__device__ __forceinline__ float sigm(float x) { return 1.f / (1.f + __expf(-x)); }
__device__ __forceinline__ float tanhf_(float x) { return 1.f - 2.f / (__expf(2.f * x) + 1.f); }

// ---------- K0: one-pass f32 -> bf16 prep (emb | Wih f,b | W_emit padded) ----------
__global__ __launch_bounds__(256) void k_prep(const float* __restrict__ emb,
    const float* __restrict__ wf, const float* __restrict__ wb, const float* __restrict__ we,
    u16* __restrict__ ebh, u16* __restrict__ wihh, u16* __restrict__ weh) {
  int i4 = (blockIdx.x * 256 + threadIdx.x) * 4;
  const float* src; u16* dst; int o;
  bool zero = false;
  if (i4 < 7680000) { src = emb + i4; dst = ebh; o = i4; }
  else if (i4 < 8204288) {
    int off = i4 - 7680000;
    src = (off < 262144) ? (wf + off) : (wb + off - 262144);
    dst = wihh; o = off;
  } else {
    int off = i4 - 8204288;
    int r = off >> 9, k = off & 511;
    dst = weh; o = off;
    if (r < 9) src = we + r * 512 + k; else { zero = true; src = we; }
  }
  f32x4 v = zero ? (f32x4){0.f, 0.f, 0.f, 0.f} : *(const f32x4*)src;
  *(unsigned*)(dst + o) = cvt_pk(v[0], v[1]);
  *(unsigned*)(dst + o + 2) = cvt_pk(v[2], v[3]);
}

// ---------- K0b: Whh f32 -> fp8 e4m3 MFMA fragments ----------
// frag T = ((dir*8+w)*64 + nt*8+ks)*64 + lane, 8 bytes each:
// B[col = w*128+nt*16+(l&15)][k = ks*32+(l>>4)*8 + 0..7]
__global__ __launch_bounds__(256) void k_prep_whh(const float* __restrict__ wf,
    const float* __restrict__ wb, char* __restrict__ whh8) {
  int T = blockIdx.x * 256 + threadIdx.x;   // 0..65535
  int l = T & 63, ks = (T >> 6) & 7, nt = (T >> 9) & 7, w = (T >> 12) & 7, dir = T >> 15;
  const float* src = dir ? wb : wf;
  int gate = w * 128 + nt * 16 + (l & 15);
  int k0 = ks * 32 + (l >> 4) * 8;
  const float* p = src + gate * 256 + k0;
  f32x4 v0 = *(const f32x4*)p, v1 = *(const f32x4*)(p + 4);
  int r0 = __builtin_amdgcn_cvt_pk_fp8_f32(v0[0], v0[1], 0, false);
  r0 = __builtin_amdgcn_cvt_pk_fp8_f32(v0[2], v0[3], r0, true);
  int r1 = __builtin_amdgcn_cvt_pk_fp8_f32(v1[0], v1[1], 0, false);
  r1 = __builtin_amdgcn_cvt_pk_fp8_f32(v1[2], v1[3], r1, true);
  ((int2*)whh8)[T] = make_int2(r0, r1);
}

// ---------- K1: chunked input GEMM (bf16, B tile LDS-staged with XOR swizzle) ----------
__global__ __launch_bounds__(256) void k_gemm_in(const int* __restrict__ ix,
    const u16* __restrict__ ebh, const u16* __restrict__ wihh,
    const float* __restrict__ bf_, const float* __restrict__ bb_,
    u16* __restrict__ xw, int c0step, int S, int logS) {
  __shared__ __align__(16) char smraw[128 * 132 * 4];
  int tid = threadIdx.x;
  int w = tid >> 6, l = tid & 63, la = l & 15, lk = (l >> 4) * 8;
  int dir = blockIdx.z;
  int m0 = blockIdx.x * 128;
  int n0 = blockIdx.y * 128;
  const char* gB = (const char*)(wihh + ((long)(dir * 1024 + n0) << 8));
#pragma unroll
  for (int it = 0; it < 16; ++it) {
    int y = it * 4096 + tid * 16;
    int sw = y ^ (((y >> 9) & 7) << 4);
    *(u32x4*)(smraw + sw) = *(const u32x4*)(gB + y);
  }
  long arow[2];
#pragma unroll
  for (int mf = 0; mf < 2; ++mf) {
    int mA = m0 + w * 32 + mf * 16 + la;
    int bA = mA >> logS, slA = mA & (S - 1);
    int sg = c0step + slA;
    int tA = dir ? (127 - sg) : sg;
    arow[mf] = (long)ix[bA * 128 + tA] << 8;
  }
  int gb[8], gx[8];
#pragma unroll
  for (int nt = 0; nt < 8; ++nt) { int g = nt * 16 + la; gb[nt] = g * 512; gx[nt] = (g & 7) << 4; }
  __syncthreads();
  f32x4 acc[2][8];
#pragma unroll
  for (int mf = 0; mf < 2; ++mf)
#pragma unroll
    for (int nt = 0; nt < 8; ++nt) acc[mf][nt] = (f32x4){0.f, 0.f, 0.f, 0.f};
#pragma unroll
  for (int ks = 0; ks < 8; ++ks) {
    int k = ks * 32 + lk;
    int kb = 2 * k;
    bf16x8 a0 = *(const bf16x8*)(ebh + arow[0] + k);
    bf16x8 a1 = *(const bf16x8*)(ebh + arow[1] + k);
#pragma unroll
    for (int nt = 0; nt < 8; ++nt) {
      bf16x8 bh = *(const bf16x8*)(smraw + gb[nt] + (kb ^ gx[nt]));
      acc[0][nt] = __builtin_amdgcn_mfma_f32_16x16x32_bf16(a0, bh, acc[0][nt], 0, 0, 0);
      acc[1][nt] = __builtin_amdgcn_mfma_f32_16x16x32_bf16(a1, bh, acc[1][nt], 0, 0, 0);
    }
  }
  __syncthreads();
  float* ot = (float*)smraw;
#pragma unroll
  for (int mf = 0; mf < 2; ++mf)
#pragma unroll
    for (int nt = 0; nt < 8; ++nt)
#pragma unroll
      for (int r = 0; r < 4; ++r)
        ot[(w * 32 + mf * 16 + (l >> 4) * 4 + r) * 132 + nt * 16 + la] = acc[mf][nt][r];
  __syncthreads();
  const float* bias = (dir ? bb_ : bf_) + n0;
  long MSd = (long)256 * S * 1024;
  int m_r0 = tid >> 4;
  int cc = (tid & 15) * 8;
  f32x4 b0 = *(const f32x4*)(bias + cc);
  f32x4 b1 = *(const f32x4*)(bias + cc + 4);
#pragma unroll
  for (int it = 0; it < 8; ++it) {
    int m_r = it * 16 + m_r0;
    f32x4 v0 = *(const f32x4*)&ot[m_r * 132 + cc];
    f32x4 v1 = *(const f32x4*)&ot[m_r * 132 + cc + 4];
    u32x4 q;
    q[0] = cvt_pk(v0[0] + b0[0], v0[1] + b0[1]);
    q[1] = cvt_pk(v0[2] + b0[2], v0[3] + b0[3]);
    q[2] = cvt_pk(v1[0] + b1[0], v1[1] + b1[1]);
    q[3] = cvt_pk(v1[2] + b1[2], v1[3] + b1[3]);
    *(u32x4*)(xw + dir * MSd + (long)(m0 + m_r) * 1024 + n0 + cc) = q;
  }
}

// ---------- K2: BiLSTM recurrence — single-block group, Whh(fp8) in VGPRs, h in LDS ----------
// 32 blocks = 2 dir x 16 batch-slices; 512 threads (8 waves, wave w owns gate rows w*128..+127).
// NOTE: __launch_bounds__(512) with NO second arg — the second arg was being interpreted as
// blocks/CU and capped VGPRs at 128, spilling the 128-VGPR weight array to scratch (round-8
// regression: 616 us). With a 256-VGPR budget the fp8 Whh fragments stay register-resident.
__global__ __launch_bounds__(512) void k_lstm(
    const char* __restrict__ whh8,
    const float* __restrict__ h0f, const float* __restrict__ c0f,
    const float* __restrict__ h0b, const float* __restrict__ c0b,
    const u16* __restrict__ xwp,
    u16* __restrict__ hf, u16* __restrict__ hb,
    float* __restrict__ cstate,
    int s0, int S, int first, int last) {
  __shared__ __align__(16) char hst8[2][16 * 264];   // fp8 h, double-buffered
  __shared__ float gl[16 * 1032];                    // gate exchange (f32)
  int bid = blockIdx.x;
  int dir = bid >> 4, bs = bid & 15;
  int tid = threadIdx.x;
  int w = tid >> 6, l = tid & 63, la = l & 15, lkb = (l >> 4) * 8;
  u16* hout = dir ? hb : hf;
  // ---- load this wave's Whh slice (fp8 fragments) into 128 VGPRs ----
  long ww[64];
  const long* wsrc = (const long*)whh8 + (long)(dir * 8 + w) * 4096;
#pragma unroll
  for (int q = 0; q < 64; ++q) ww[q] = wsrc[q * 64 + l];
  // ---- per-thread epilogue identity: batch row bl, 8 j starting at jj8 ----
  int bl = tid >> 5, jj8 = (tid & 31) * 8;
  int b_g = bs * 16 + bl;
  float cr[8];
  {
    const float* csrc = first ? ((dir ? c0b : c0f) + b_g * 256 + jj8)
                              : (cstate + ((long)(dir * 256 + b_g)) * 256 + jj8);
    f32x4 c0v = *(const f32x4*)csrc;
    f32x4 c1v = *(const f32x4*)(csrc + 4);
#pragma unroll
    for (int e = 0; e < 4; ++e) { cr[e] = c0v[e]; cr[4 + e] = c1v[e]; }
  }
  // ---- init hst8[0] with h(t before s0) ----
  {
    int r0, r1;
    if (first) {
      const float* p = (dir ? h0b : h0f) + b_g * 256 + jj8;
      f32x4 v0 = *(const f32x4*)p, v1 = *(const f32x4*)(p + 4);
      r0 = __builtin_amdgcn_cvt_pk_fp8_f32(v0[0], v0[1], 0, false);
      r0 = __builtin_amdgcn_cvt_pk_fp8_f32(v0[2], v0[3], r0, true);
      r1 = __builtin_amdgcn_cvt_pk_fp8_f32(v1[0], v1[1], 0, false);
      r1 = __builtin_amdgcn_cvt_pk_fp8_f32(v1[2], v1[3], r1, true);
    } else {
      int tp = dir ? (127 - s0 + 1) : (s0 - 1);
      const u16* p = hout + ((long)b_g * 128 + tp) * 256 + jj8;
      u32x4 q = *(const u32x4*)p;
      r0 = __builtin_amdgcn_cvt_pk_fp8_f32(bflo(q[0]), bfhi(q[0]), 0, false);
      r0 = __builtin_amdgcn_cvt_pk_fp8_f32(bflo(q[1]), bfhi(q[1]), r0, true);
      r1 = __builtin_amdgcn_cvt_pk_fp8_f32(bflo(q[2]), bfhi(q[2]), 0, false);
      r1 = __builtin_amdgcn_cvt_pk_fp8_f32(bflo(q[3]), bfhi(q[3]), r1, true);
    }
    *(int2*)&hst8[0][bl * 264 + jj8] = make_int2(r0, r1);
  }
  long dirMS = (long)dir * 256 * S * 1024;
  __syncthreads();
  int p = 0;
  for (int sl = 0; sl < S; ++sl) {
    int sg = s0 + sl;
    int t_io = dir ? 127 - sg : sg;
    // xw prefetch (hidden under MFMA phase)
    long xbase = dirMS + ((long)b_g * S + sl) * 1024 + jj8;
    u32x4 xi = *(const u32x4*)(xwp + xbase);
    u32x4 xf = *(const u32x4*)(xwp + xbase + 256);
    u32x4 xg = *(const u32x4*)(xwp + xbase + 512);
    u32x4 xo = *(const u32x4*)(xwp + xbase + 768);
    // ---- MFMA phase: gates[w*128 .. +127][16 batch] ----
    const char* hp = hst8[p];
    f32x4 acc[8];
#pragma unroll
    for (int nt = 0; nt < 8; ++nt) acc[nt] = (f32x4){0.f, 0.f, 0.f, 0.f};
#pragma unroll
    for (int ks = 0; ks < 8; ++ks) {
      long av = *(const long*)(hp + la * 264 + ks * 32 + lkb);
#pragma unroll
      for (int nt = 0; nt < 8; ++nt)
        acc[nt] = __builtin_amdgcn_mfma_f32_16x16x32_fp8_fp8(av, ww[nt * 8 + ks], acc[nt], 0, 0, 0);
    }
#pragma unroll
    for (int nt = 0; nt < 8; ++nt)
#pragma unroll
      for (int r = 0; r < 4; ++r)
        gl[((l >> 4) * 4 + r) * 1032 + w * 128 + nt * 16 + la] = acc[nt][r];
    __syncthreads();
    // ---- epilogue: 8 j per thread ----
    const float* g0 = &gl[bl * 1032 + jj8];
    f32x4 aI0 = *(const f32x4*)(g0);         f32x4 aI1 = *(const f32x4*)(g0 + 4);
    f32x4 aF0 = *(const f32x4*)(g0 + 256);   f32x4 aF1 = *(const f32x4*)(g0 + 260);
    f32x4 aG0 = *(const f32x4*)(g0 + 512);   f32x4 aG1 = *(const f32x4*)(g0 + 516);
    f32x4 aO0 = *(const f32x4*)(g0 + 768);   f32x4 aO1 = *(const f32x4*)(g0 + 772);
    float hv[8];
#pragma unroll
    for (int e = 0; e < 4; ++e) {
      float gi = aI0[e] + ((e & 1) ? bfhi(xi[e >> 1]) : bflo(xi[e >> 1]));
      float gf = aF0[e] + ((e & 1) ? bfhi(xf[e >> 1]) : bflo(xf[e >> 1]));
      float gg = aG0[e] + ((e & 1) ? bfhi(xg[e >> 1]) : bflo(xg[e >> 1]));
      float go = aO0[e] + ((e & 1) ? bfhi(xo[e >> 1]) : bflo(xo[e >> 1]));
      float c = sigm(gf) * cr[e] + sigm(gi) * tanhf_(gg);
      cr[e] = c; hv[e] = sigm(go) * tanhf_(c);
    }
#pragma unroll
    for (int e = 0; e < 4; ++e) {
      float gi = aI1[e] + ((e & 1) ? bfhi(xi[2 + (e >> 1)]) : bflo(xi[2 + (e >> 1)]));
      float gf = aF1[e] + ((e & 1) ? bfhi(xf[2 + (e >> 1)]) : bflo(xf[2 + (e >> 1)]));
      float gg = aG1[e] + ((e & 1) ? bfhi(xg[2 + (e >> 1)]) : bflo(xg[2 + (e >> 1)]));
      float go = aO1[e] + ((e & 1) ? bfhi(xo[2 + (e >> 1)]) : bflo(xo[2 + (e >> 1)]));
      float c = sigm(gf) * cr[4 + e] + sigm(gi) * tanhf_(gg);
      cr[4 + e] = c; hv[4 + e] = sigm(go) * tanhf_(c);
    }
    // h -> fp8 LDS (next step's A) + bf16 global (for emission; fire-and-forget)
    int r0 = __builtin_amdgcn_cvt_pk_fp8_f32(hv[0], hv[1], 0, false);
    r0 = __builtin_amdgcn_cvt_pk_fp8_f32(hv[2], hv[3], r0, true);
    int r1 = __builtin_amdgcn_cvt_pk_fp8_f32(hv[4], hv[5], 0, false);
    r1 = __builtin_amdgcn_cvt_pk_fp8_f32(hv[6], hv[7], r1, true);
    *(int2*)&hst8[p ^ 1][bl * 264 + jj8] = make_int2(r0, r1);
    u32x4 hq;
    hq[0] = cvt_pk(hv[0], hv[1]); hq[1] = cvt_pk(hv[2], hv[3]);
    hq[2] = cvt_pk(hv[4], hv[5]); hq[3] = cvt_pk(hv[6], hv[7]);
    *(u32x4*)(hout + ((long)b_g * 128 + t_io) * 256 + jj8) = hq;
    __syncthreads();
    p ^= 1;
  }
  if (!last) {
    float* cd = cstate + ((long)(dir * 256 + b_g)) * 256 + jj8;
    f32x4 c0v, c1v;
#pragma unroll
    for (int e = 0; e < 4; ++e) { c0v[e] = cr[e]; c1v[e] = cr[4 + e]; }
    *(f32x4*)cd = c0v;
    *(f32x4*)(cd + 4) = c1v;
  }
}

// ---------- K3: emission (also zero-inits out[0] for the tail's atomic loss sum) ----------
__global__ __launch_bounds__(256) void k_emis(const u16* __restrict__ hfb, const u16* __restrict__ hbb,
    const u16* __restrict__ weh, const float* __restrict__ bemit, float* __restrict__ emis,
    float* __restrict__ out) {
  if (blockIdx.x == 0 && threadIdx.x == 0) out[0] = 0.f;
  int w = threadIdx.x >> 6, l = threadIdx.x & 63;
  int la = l & 15, lk = (l >> 4) * 8;
  long m0 = (long)blockIdx.x * 64 + w * 16;
  long am = m0 + la;
  f32x4 acc = (f32x4){0.f, 0.f, 0.f, 0.f};
#pragma unroll
  for (int ks = 0; ks < 16; ++ks) {
    int k = ks * 32 + lk;
    const u16* src = (k < 256) ? (hfb + am * 256 + k) : (hbb + am * 256 + (k - 256));
    bf16x8 ah = *(const bf16x8*)src;
    bf16x8 bh = *(const bf16x8*)(weh + la * 512 + k);
    acc = __builtin_amdgcn_mfma_f32_16x16x32_bf16(ah, bh, acc, 0, 0, 0);
  }
  int kout = la;
  float bias = (kout < 9) ? bemit[kout] : 0.f;
  long mr = m0 + (l >> 4) * 4;
#pragma unroll
  for (int r = 0; r < 4; ++r)
    emis[(mr + r) * 16 + kout] = acc[r] + bias;
}

// ---------- K4: fused tail ----------
__global__ __launch_bounds__(256) void k_tail(const float* __restrict__ emis, const int* __restrict__ ixin,
    const int* __restrict__ label, const float* __restrict__ startt, const float* __restrict__ endt,
    const float* __restrict__ trans, float* __restrict__ out) {
  __shared__ float al_s[16][16];
  __shared__ float tr_s[9][16];
  __shared__ float num_s[16];
  __shared__ float red_s[16];
  __shared__ unsigned char bpl[16 * 127 * 16];
  int tid = threadIdx.x, bl = tid >> 4, k = tid & 15;
  int bid = blockIdx.x;
  if (bl < 9) tr_s[bl][k] = (k < 9) ? trans[bl * 9 + k] : 0.f;
  if (bid < 16) {
    int b = bid * 16 + bl;
    float a = 0.f, num = 0.f;
    int lastlab = 0;
    if (k < 9) a = startt[k] + emis[((long)b * 128) * 16 + k];
    al_s[bl][k] = a;
    if (k == 9) {
      int l0 = label[b * 128];
      num = startt[l0] + emis[((long)b * 128) * 16 + l0];
      lastlab = l0;
    }
    __syncthreads();
    for (int t = 1; t < 128; ++t) {
      bool msk = ixin[b * 128 + t] != 0;
      float anew = a;
      if (k < 9) {
        float mx = -1e30f;
#pragma unroll
        for (int j = 0; j < 9; ++j) mx = fmaxf(mx, al_s[bl][j] + tr_s[j][k]);
        float ss = 0.f;
#pragma unroll
        for (int j = 0; j < 9; ++j) ss += __expf(al_s[bl][j] + tr_s[j][k] - mx);
        anew = mx + __logf(ss) + emis[((long)b * 128 + t) * 16 + k];
        if (!msk) anew = a;
      } else if (k == 9 && msk) {
        int lt = label[b * 128 + t];
        num += tr_s[lastlab][lt] + emis[((long)b * 128 + t) * 16 + lt];
        lastlab = lt;
      }
      __syncthreads();
      if (k < 9) { a = anew; al_s[bl][k] = a; }
      __syncthreads();
    }
    if (k == 9) num_s[bl] = num + endt[lastlab];
    __syncthreads();
    if (k == 0) {
      float mx = -1e30f;
#pragma unroll
      for (int j = 0; j < 9; ++j) mx = fmaxf(mx, al_s[bl][j] + endt[j]);
      float ss = 0.f;
#pragma unroll
      for (int j = 0; j < 9; ++j) ss += __expf(al_s[bl][j] + endt[j] - mx);
      red_s[bl] = (mx + __logf(ss)) - num_s[bl];
    }
    __syncthreads();
    if (tid == 0) {
      float s = 0.f;
      for (int i = 0; i < 16; ++i) s += red_s[i];
      atomicAdd(out, s);
    }
  } else {
    int vb = bid - 16;
    int b = vb * 16 + bl;
    float v = -1e30f;
    if (k < 9) v = startt[k] + emis[((long)b * 128) * 16 + k];
    al_s[bl][k] = v;
    __syncthreads();
    for (int t = 1; t < 128; ++t) {
      float vnew = v;
      if (k < 9) {
        float best = -1e30f; int bi = 0;
#pragma unroll
        for (int j = 0; j < 9; ++j) {
          float tot = al_s[bl][j] + tr_s[j][k];
          if (tot > best) { best = tot; bi = j; }
        }
        vnew = best + emis[((long)b * 128 + t) * 16 + k];
        bpl[(bl * 127 + (t - 1)) * 16 + k] = (unsigned char)bi;
      }
      __syncthreads();
      if (k < 9) { v = vnew; al_s[bl][k] = v; }
      __syncthreads();
    }
    if (tid < 16) {
      int bb = vb * 16 + tid;
      float best = -1e30f; int tag = 0;
#pragma unroll
      for (int j = 0; j < 9; ++j) {
        float vv = al_s[tid][j] + endt[j];
        if (vv > best) { best = vv; tag = j; }
      }
      out[1 + bb * 128 + 127] = (float)tag;
      for (int t = 127; t >= 1; --t) {
        tag = bpl[(tid * 127 + (t - 1)) * 16 + tag];
        out[1 + bb * 128 + t - 1] = (float)tag;
      }
    }
  }
}

__global__ void k_sent(float* out) { out[0] = -1.0e6f; }

// ---------- launch ----------
extern "C" void kernel_launch(void* const* d_in, const int* in_sizes, int n_in,
                              void* d_out, int out_size, void* d_ws, size_t ws_size,
                              hipStream_t stream) {
  const int* in_x    = (const int*)d_in[0];
  const int* label   = (const int*)d_in[1];
  const float* emb   = (const float*)d_in[2];
  const float* Wih_f = (const float*)d_in[3];
  const float* Whh_f = (const float*)d_in[4];
  const float* b_f   = (const float*)d_in[5];
  const float* Wih_b = (const float*)d_in[6];
  const float* Whh_b = (const float*)d_in[7];
  const float* b_b   = (const float*)d_in[8];
  const float* W_emit= (const float*)d_in[9];
  const float* b_emit= (const float*)d_in[10];
  const float* start_t=(const float*)d_in[11];
  const float* end_t = (const float*)d_in[12];
  const float* trans = (const float*)d_in[13];
  const float* h0f   = (const float*)d_in[14];
  const float* c0f   = (const float*)d_in[15];
  const float* h0b   = (const float*)d_in[16];
  const float* c0b   = (const float*)d_in[17];
  (void)in_sizes; (void)n_in; (void)out_size;

  auto align = [](size_t x) { return (x + 255) & ~(size_t)255; };
  size_t fixed = 0;
  fixed += align(32768L * 256 * 2);   // HF bf16
  fixed += align(32768L * 256 * 2);   // HB bf16
  fixed += align(30000L * 256 * 2);   // EBH
  fixed += align(2048L * 256 * 2);    // WIHH bf16
  fixed += align(16L * 512 * 2);      // WEH
  fixed += align(2048L * 256);        // WHH8 fp8
  fixed += align(32768L * 16 * 4);    // EMIS
  fixed += align(2L * 256 * 256 * 4); // CSTATE

  int S = 0;
  const int cands[4] = {128, 64, 32, 16};
  for (int ci = 0; ci < 4; ++ci) {
    size_t xb = align(1048576L * cands[ci]);
    if (xb + fixed <= ws_size) { S = cands[ci]; break; }
  }
  if (S == 0) { k_sent<<<1, 1, 0, stream>>>((float*)d_out); return; }
  int logS = __builtin_ctz(S);
  int NC = 128 / S;

  char* ws = (char*)d_ws;
  size_t o = 0;
  auto alloc = [&](size_t sz) { size_t r = o; o += (sz + 255) & ~(size_t)255; return r; };
  u16* xw    = (u16*)(ws + alloc(1048576L * S));
  u16* hf    = (u16*)(ws + alloc(32768L * 256 * 2));
  u16* hb    = (u16*)(ws + alloc(32768L * 256 * 2));
  u16* ebh   = (u16*)(ws + alloc(30000L * 256 * 2));
  u16* wihh  = (u16*)(ws + alloc(2048L * 256 * 2));
  u16* weh   = (u16*)(ws + alloc(16L * 512 * 2));
  char* whh8 = (char*)(ws + alloc(2048L * 256));
  float* emis= (float*)(ws + alloc(32768L * 16 * 4));
  float* cstate = (float*)(ws + alloc(2L * 256 * 256 * 4));

  k_prep<<<8020, 256, 0, stream>>>(emb, Wih_f, Wih_b, W_emit, ebh, wihh, weh);
  k_prep_whh<<<256, 256, 0, stream>>>(Whh_f, Whh_b, whh8);
  for (int c = 0; c < NC; ++c) {
    k_gemm_in<<<dim3(2 * S, 8, 2), 256, 0, stream>>>(in_x, ebh, wihh, b_f, b_b,
                                                     xw, c * S, S, logS);
    k_lstm<<<32, 512, 0, stream>>>(whh8, h0f, c0f, h0b, c0b, xw, hf, hb,
                                   cstate, c * S, S, c == 0 ? 1 : 0, c == NC - 1 ? 1 : 0);
  }
  k_emis<<<512, 256, 0, stream>>>(hf, hb, weh, b_emit, emis, (float*)d_out);
  k_tail<<<32, 256, 0, stream>>>(emis, in_x, label, start_t, end_t, trans, (float*)d_out);
}

// Round 10
// 670.563 us; speedup vs baseline: 1.1205x; 1.1205x over previous
//
#include <hip/hip_runtime.h>

typedef __attribute__((ext_vector_type(8))) short bf16x8;
typedef __attribute__((ext_vector_type(4))) float f32x4;
typedef __attribute__((ext_vector_type(4))) unsigned u32x4;
typedef unsigned short u16;

// ---------- helpers ----------
__device__ __forceinline__ unsigned cvt_pk(float lo, float hi) {
  unsigned r;
  asm("v_cvt_pk_bf16_f32 %0, %1, %2" : "=v"(r) : "v"(lo), "v"(hi));
  return r;
}
__device__ __forceinline__ float bflo(unsigned d) { return __uint_as_float(d << 16); }
__device__ __forceinline__ float bfhi(unsigned d) { return __uint_as_float(d & 0xffff0000u); }
__device__ __forceinline__ float sigm(float x) { return 1.f / (1.f + __expf(-x)); }
__device__ __forceinline__ float tanhf_(float x) { return 1.f - 2.f / (__expf(2.f * x) + 1.f); }

// ---------- K0: one-pass f32 -> bf16 prep (emb | Wih f,b | W_emit padded) ----------
__global__ __launch_bounds__(256) void k_prep(const float* __restrict__ emb,
    const float* __restrict__ wf, const float* __restrict__ wb, const float* __restrict__ we,
    u16* __restrict__ ebh, u16* __restrict__ wihh, u16* __restrict__ weh) {
  int i4 = (blockIdx.x * 256 + threadIdx.x) * 4;
  const float* src; u16* dst; int o;
  bool zero = false;
  if (i4 < 7680000) { src = emb + i4; dst = ebh; o = i4; }
  else if (i4 < 8204288) {
    int off = i4 - 7680000;
    src = (off < 262144) ? (wf + off) : (wb + off - 262144);
    dst = wihh; o = off;
  } else {
    int off = i4 - 8204288;
    int r = off >> 9, k = off & 511;
    dst = weh; o = off;
    if (r < 9) src = we + r * 512 + k; else { zero = true; src = we; }
  }
  f32x4 v = zero ? (f32x4){0.f, 0.f, 0.f, 0.f} : *(const f32x4*)src;
  *(unsigned*)(dst + o) = cvt_pk(v[0], v[1]);
  *(unsigned*)(dst + o + 2) = cvt_pk(v[2], v[3]);
}

// ---------- K0b: Whh f32 -> fp8 e4m3 MFMA fragments ----------
// frag T = ((dir*8+w)*64 + nt*8+ks)*64 + lane, 8 bytes each:
// B[col = w*128+nt*16+(l&15)][k = ks*32+(l>>4)*8 + 0..7]
__global__ __launch_bounds__(256) void k_prep_whh(const float* __restrict__ wf,
    const float* __restrict__ wb, char* __restrict__ whh8) {
  int T = blockIdx.x * 256 + threadIdx.x;   // 0..65535
  int l = T & 63, ks = (T >> 6) & 7, nt = (T >> 9) & 7, w = (T >> 12) & 7, dir = T >> 15;
  const float* src = dir ? wb : wf;
  int gate = w * 128 + nt * 16 + (l & 15);
  int k0 = ks * 32 + (l >> 4) * 8;
  const float* p = src + gate * 256 + k0;
  f32x4 v0 = *(const f32x4*)p, v1 = *(const f32x4*)(p + 4);
  int r0 = __builtin_amdgcn_cvt_pk_fp8_f32(v0[0], v0[1], 0, false);
  r0 = __builtin_amdgcn_cvt_pk_fp8_f32(v0[2], v0[3], r0, true);
  int r1 = __builtin_amdgcn_cvt_pk_fp8_f32(v1[0], v1[1], 0, false);
  r1 = __builtin_amdgcn_cvt_pk_fp8_f32(v1[2], v1[3], r1, true);
  ((int2*)whh8)[T] = make_int2(r0, r1);
}

// ---------- K1: chunked input GEMM (bf16, B tile LDS-staged with XOR swizzle) ----------
__global__ __launch_bounds__(256) void k_gemm_in(const int* __restrict__ ix,
    const u16* __restrict__ ebh, const u16* __restrict__ wihh,
    const float* __restrict__ bf_, const float* __restrict__ bb_,
    u16* __restrict__ xw, int c0step, int S, int logS) {
  __shared__ __align__(16) char smraw[128 * 132 * 4];
  int tid = threadIdx.x;
  int w = tid >> 6, l = tid & 63, la = l & 15, lk = (l >> 4) * 8;
  int dir = blockIdx.z;
  int m0 = blockIdx.x * 128;
  int n0 = blockIdx.y * 128;
  const char* gB = (const char*)(wihh + ((long)(dir * 1024 + n0) << 8));
#pragma unroll
  for (int it = 0; it < 16; ++it) {
    int y = it * 4096 + tid * 16;
    int sw = y ^ (((y >> 9) & 7) << 4);
    *(u32x4*)(smraw + sw) = *(const u32x4*)(gB + y);
  }
  long arow[2];
#pragma unroll
  for (int mf = 0; mf < 2; ++mf) {
    int mA = m0 + w * 32 + mf * 16 + la;
    int bA = mA >> logS, slA = mA & (S - 1);
    int sg = c0step + slA;
    int tA = dir ? (127 - sg) : sg;
    arow[mf] = (long)ix[bA * 128 + tA] << 8;
  }
  int gb[8], gx[8];
#pragma unroll
  for (int nt = 0; nt < 8; ++nt) { int g = nt * 16 + la; gb[nt] = g * 512; gx[nt] = (g & 7) << 4; }
  __syncthreads();
  f32x4 acc[2][8];
#pragma unroll
  for (int mf = 0; mf < 2; ++mf)
#pragma unroll
    for (int nt = 0; nt < 8; ++nt) acc[mf][nt] = (f32x4){0.f, 0.f, 0.f, 0.f};
#pragma unroll
  for (int ks = 0; ks < 8; ++ks) {
    int k = ks * 32 + lk;
    int kb = 2 * k;
    bf16x8 a0 = *(const bf16x8*)(ebh + arow[0] + k);
    bf16x8 a1 = *(const bf16x8*)(ebh + arow[1] + k);
#pragma unroll
    for (int nt = 0; nt < 8; ++nt) {
      bf16x8 bh = *(const bf16x8*)(smraw + gb[nt] + (kb ^ gx[nt]));
      acc[0][nt] = __builtin_amdgcn_mfma_f32_16x16x32_bf16(a0, bh, acc[0][nt], 0, 0, 0);
      acc[1][nt] = __builtin_amdgcn_mfma_f32_16x16x32_bf16(a1, bh, acc[1][nt], 0, 0, 0);
    }
  }
  __syncthreads();
  float* ot = (float*)smraw;
#pragma unroll
  for (int mf = 0; mf < 2; ++mf)
#pragma unroll
    for (int nt = 0; nt < 8; ++nt)
#pragma unroll
      for (int r = 0; r < 4; ++r)
        ot[(w * 32 + mf * 16 + (l >> 4) * 4 + r) * 132 + nt * 16 + la] = acc[mf][nt][r];
  __syncthreads();
  const float* bias = (dir ? bb_ : bf_) + n0;
  long MSd = (long)256 * S * 1024;
  int m_r0 = tid >> 4;
  int cc = (tid & 15) * 8;
  f32x4 b0 = *(const f32x4*)(bias + cc);
  f32x4 b1 = *(const f32x4*)(bias + cc + 4);
#pragma unroll
  for (int it = 0; it < 8; ++it) {
    int m_r = it * 16 + m_r0;
    f32x4 v0 = *(const f32x4*)&ot[m_r * 132 + cc];
    f32x4 v1 = *(const f32x4*)&ot[m_r * 132 + cc + 4];
    u32x4 q;
    q[0] = cvt_pk(v0[0] + b0[0], v0[1] + b0[1]);
    q[1] = cvt_pk(v0[2] + b0[2], v0[3] + b0[3]);
    q[2] = cvt_pk(v1[0] + b1[0], v1[1] + b1[1]);
    q[3] = cvt_pk(v1[2] + b1[2], v1[3] + b1[3]);
    *(u32x4*)(xw + dir * MSd + (long)(m0 + m_r) * 1024 + n0 + cc) = q;
  }
}

// ---------- K2: BiLSTM recurrence — single-block group, Whh(fp8) in VGPRs, h in LDS ----------
// 32 blocks = 2 dir x 16 batch-slices; 512 threads (8 waves, wave w owns gate rows w*128..+127).
// VGPR-budget forcing (round 8/9 postmortem: allocator derives occupancy target from LDS and
// capped VGPRs at 128, spilling the 128-VGPR fp8 weight array to scratch -> 616 us):
//  (a) amdgpu_waves_per_eu(2,2) -> 256-VGPR budget (8-wave blocks always place 2 waves/SIMD);
//  (b) LDS bumped to 85,248 B (>80 KiB) -> 1 workgroup/CU by LDS -> same 2 waves/SIMD target.
#define GLW 1200
__global__ __launch_bounds__(512) __attribute__((amdgpu_waves_per_eu(2, 2))) void k_lstm(
    const char* __restrict__ whh8,
    const float* __restrict__ h0f, const float* __restrict__ c0f,
    const float* __restrict__ h0b, const float* __restrict__ c0b,
    const u16* __restrict__ xwp,
    u16* __restrict__ hf, u16* __restrict__ hb,
    float* __restrict__ cstate,
    int s0, int S, int first, int last) {
  __shared__ __align__(16) char hst8[2][16 * 264];   // fp8 h, double-buffered (8448 B)
  __shared__ float gl[16 * GLW];                     // gate exchange f32 (76800 B)
  int bid = blockIdx.x;
  int dir = bid >> 4, bs = bid & 15;
  int tid = threadIdx.x;
  int w = tid >> 6, l = tid & 63, la = l & 15, lkb = (l >> 4) * 8;
  u16* hout = dir ? hb : hf;
  // ---- load this wave's Whh slice (fp8 fragments) into 128 VGPRs ----
  long ww[64];
  const long* wsrc = (const long*)whh8 + (long)(dir * 8 + w) * 4096;
#pragma unroll
  for (int q = 0; q < 64; ++q) ww[q] = wsrc[q * 64 + l];
  // ---- per-thread epilogue identity: batch row bl, 8 j starting at jj8 ----
  int bl = tid >> 5, jj8 = (tid & 31) * 8;
  int b_g = bs * 16 + bl;
  float cr[8];
  {
    const float* csrc = first ? ((dir ? c0b : c0f) + b_g * 256 + jj8)
                              : (cstate + ((long)(dir * 256 + b_g)) * 256 + jj8);
    f32x4 c0v = *(const f32x4*)csrc;
    f32x4 c1v = *(const f32x4*)(csrc + 4);
#pragma unroll
    for (int e = 0; e < 4; ++e) { cr[e] = c0v[e]; cr[4 + e] = c1v[e]; }
  }
  // ---- init hst8[0] with h(t before s0) ----
  {
    int r0, r1;
    if (first) {
      const float* p = (dir ? h0b : h0f) + b_g * 256 + jj8;
      f32x4 v0 = *(const f32x4*)p, v1 = *(const f32x4*)(p + 4);
      r0 = __builtin_amdgcn_cvt_pk_fp8_f32(v0[0], v0[1], 0, false);
      r0 = __builtin_amdgcn_cvt_pk_fp8_f32(v0[2], v0[3], r0, true);
      r1 = __builtin_amdgcn_cvt_pk_fp8_f32(v1[0], v1[1], 0, false);
      r1 = __builtin_amdgcn_cvt_pk_fp8_f32(v1[2], v1[3], r1, true);
    } else {
      int tp = dir ? (127 - s0 + 1) : (s0 - 1);
      const u16* p = hout + ((long)b_g * 128 + tp) * 256 + jj8;
      u32x4 q = *(const u32x4*)p;
      r0 = __builtin_amdgcn_cvt_pk_fp8_f32(bflo(q[0]), bfhi(q[0]), 0, false);
      r0 = __builtin_amdgcn_cvt_pk_fp8_f32(bflo(q[1]), bfhi(q[1]), r0, true);
      r1 = __builtin_amdgcn_cvt_pk_fp8_f32(bflo(q[2]), bfhi(q[2]), 0, false);
      r1 = __builtin_amdgcn_cvt_pk_fp8_f32(bflo(q[3]), bfhi(q[3]), r1, true);
    }
    *(int2*)&hst8[0][bl * 264 + jj8] = make_int2(r0, r1);
  }
  long dirMS = (long)dir * 256 * S * 1024;
  __syncthreads();
  int p = 0;
  for (int sl = 0; sl < S; ++sl) {
    int sg = s0 + sl;
    int t_io = dir ? 127 - sg : sg;
    // xw prefetch (hidden under MFMA phase)
    long xbase = dirMS + ((long)b_g * S + sl) * 1024 + jj8;
    u32x4 xi = *(const u32x4*)(xwp + xbase);
    u32x4 xf = *(const u32x4*)(xwp + xbase + 256);
    u32x4 xg = *(const u32x4*)(xwp + xbase + 512);
    u32x4 xo = *(const u32x4*)(xwp + xbase + 768);
    // ---- MFMA phase: gates[w*128 .. +127][16 batch] ----
    const char* hp = hst8[p];
    f32x4 acc[8];
#pragma unroll
    for (int nt = 0; nt < 8; ++nt) acc[nt] = (f32x4){0.f, 0.f, 0.f, 0.f};
#pragma unroll
    for (int ks = 0; ks < 8; ++ks) {
      long av = *(const long*)(hp + la * 264 + ks * 32 + lkb);
#pragma unroll
      for (int nt = 0; nt < 8; ++nt)
        acc[nt] = __builtin_amdgcn_mfma_f32_16x16x32_fp8_fp8(av, ww[nt * 8 + ks], acc[nt], 0, 0, 0);
    }
#pragma unroll
    for (int nt = 0; nt < 8; ++nt)
#pragma unroll
      for (int r = 0; r < 4; ++r)
        gl[((l >> 4) * 4 + r) * GLW + w * 128 + nt * 16 + la] = acc[nt][r];
    __syncthreads();
    // ---- epilogue: 8 j per thread ----
    const float* g0 = &gl[bl * GLW + jj8];
    f32x4 aI0 = *(const f32x4*)(g0);         f32x4 aI1 = *(const f32x4*)(g0 + 4);
    f32x4 aF0 = *(const f32x4*)(g0 + 256);   f32x4 aF1 = *(const f32x4*)(g0 + 260);
    f32x4 aG0 = *(const f32x4*)(g0 + 512);   f32x4 aG1 = *(const f32x4*)(g0 + 516);
    f32x4 aO0 = *(const f32x4*)(g0 + 768);   f32x4 aO1 = *(const f32x4*)(g0 + 772);
    float hv[8];
#pragma unroll
    for (int e = 0; e < 4; ++e) {
      float gi = aI0[e] + ((e & 1) ? bfhi(xi[e >> 1]) : bflo(xi[e >> 1]));
      float gf = aF0[e] + ((e & 1) ? bfhi(xf[e >> 1]) : bflo(xf[e >> 1]));
      float gg = aG0[e] + ((e & 1) ? bfhi(xg[e >> 1]) : bflo(xg[e >> 1]));
      float go = aO0[e] + ((e & 1) ? bfhi(xo[e >> 1]) : bflo(xo[e >> 1]));
      float c = sigm(gf) * cr[e] + sigm(gi) * tanhf_(gg);
      cr[e] = c; hv[e] = sigm(go) * tanhf_(c);
    }
#pragma unroll
    for (int e = 0; e < 4; ++e) {
      float gi = aI1[e] + ((e & 1) ? bfhi(xi[2 + (e >> 1)]) : bflo(xi[2 + (e >> 1)]));
      float gf = aF1[e] + ((e & 1) ? bfhi(xf[2 + (e >> 1)]) : bflo(xf[2 + (e >> 1)]));
      float gg = aG1[e] + ((e & 1) ? bfhi(xg[2 + (e >> 1)]) : bflo(xg[2 + (e >> 1)]));
      float go = aO1[e] + ((e & 1) ? bfhi(xo[2 + (e >> 1)]) : bflo(xo[2 + (e >> 1)]));
      float c = sigm(gf) * cr[4 + e] + sigm(gi) * tanhf_(gg);
      cr[4 + e] = c; hv[4 + e] = sigm(go) * tanhf_(c);
    }
    // h -> fp8 LDS (next step's A) + bf16 global (for emission; fire-and-forget)
    int r0 = __builtin_amdgcn_cvt_pk_fp8_f32(hv[0], hv[1], 0, false);
    r0 = __builtin_amdgcn_cvt_pk_fp8_f32(hv[2], hv[3], r0, true);
    int r1 = __builtin_amdgcn_cvt_pk_fp8_f32(hv[4], hv[5], 0, false);
    r1 = __builtin_amdgcn_cvt_pk_fp8_f32(hv[6], hv[7], r1, true);
    *(int2*)&hst8[p ^ 1][bl * 264 + jj8] = make_int2(r0, r1);
    u32x4 hq;
    hq[0] = cvt_pk(hv[0], hv[1]); hq[1] = cvt_pk(hv[2], hv[3]);
    hq[2] = cvt_pk(hv[4], hv[5]); hq[3] = cvt_pk(hv[6], hv[7]);
    *(u32x4*)(hout + ((long)b_g * 128 + t_io) * 256 + jj8) = hq;
    __syncthreads();
    p ^= 1;
  }
  if (!last) {
    float* cd = cstate + ((long)(dir * 256 + b_g)) * 256 + jj8;
    f32x4 c0v, c1v;
#pragma unroll
    for (int e = 0; e < 4; ++e) { c0v[e] = cr[e]; c1v[e] = cr[4 + e]; }
    *(f32x4*)cd = c0v;
    *(f32x4*)(cd + 4) = c1v;
  }
}

// ---------- K3: emission (also zero-inits out[0] for the tail's atomic loss sum) ----------
__global__ __launch_bounds__(256) void k_emis(const u16* __restrict__ hfb, const u16* __restrict__ hbb,
    const u16* __restrict__ weh, const float* __restrict__ bemit, float* __restrict__ emis,
    float* __restrict__ out) {
  if (blockIdx.x == 0 && threadIdx.x == 0) out[0] = 0.f;
  int w = threadIdx.x >> 6, l = threadIdx.x & 63;
  int la = l & 15, lk = (l >> 4) * 8;
  long m0 = (long)blockIdx.x * 64 + w * 16;
  long am = m0 + la;
  f32x4 acc = (f32x4){0.f, 0.f, 0.f, 0.f};
#pragma unroll
  for (int ks = 0; ks < 16; ++ks) {
    int k = ks * 32 + lk;
    const u16* src = (k < 256) ? (hfb + am * 256 + k) : (hbb + am * 256 + (k - 256));
    bf16x8 ah = *(const bf16x8*)src;
    bf16x8 bh = *(const bf16x8*)(weh + la * 512 + k);
    acc = __builtin_amdgcn_mfma_f32_16x16x32_bf16(ah, bh, acc, 0, 0, 0);
  }
  int kout = la;
  float bias = (kout < 9) ? bemit[kout] : 0.f;
  long mr = m0 + (l >> 4) * 4;
#pragma unroll
  for (int r = 0; r < 4; ++r)
    emis[(mr + r) * 16 + kout] = acc[r] + bias;
}

// ---------- K4: fused tail ----------
__global__ __launch_bounds__(256) void k_tail(const float* __restrict__ emis, const int* __restrict__ ixin,
    const int* __restrict__ label, const float* __restrict__ startt, const float* __restrict__ endt,
    const float* __restrict__ trans, float* __restrict__ out) {
  __shared__ float al_s[16][16];
  __shared__ float tr_s[9][16];
  __shared__ float num_s[16];
  __shared__ float red_s[16];
  __shared__ unsigned char bpl[16 * 127 * 16];
  int tid = threadIdx.x, bl = tid >> 4, k = tid & 15;
  int bid = blockIdx.x;
  if (bl < 9) tr_s[bl][k] = (k < 9) ? trans[bl * 9 + k] : 0.f;
  if (bid < 16) {
    int b = bid * 16 + bl;
    float a = 0.f, num = 0.f;
    int lastlab = 0;
    if (k < 9) a = startt[k] + emis[((long)b * 128) * 16 + k];
    al_s[bl][k] = a;
    if (k == 9) {
      int l0 = label[b * 128];
      num = startt[l0] + emis[((long)b * 128) * 16 + l0];
      lastlab = l0;
    }
    __syncthreads();
    for (int t = 1; t < 128; ++t) {
      bool msk = ixin[b * 128 + t] != 0;
      float anew = a;
      if (k < 9) {
        float mx = -1e30f;
#pragma unroll
        for (int j = 0; j < 9; ++j) mx = fmaxf(mx, al_s[bl][j] + tr_s[j][k]);
        float ss = 0.f;
#pragma unroll
        for (int j = 0; j < 9; ++j) ss += __expf(al_s[bl][j] + tr_s[j][k] - mx);
        anew = mx + __logf(ss) + emis[((long)b * 128 + t) * 16 + k];
        if (!msk) anew = a;
      } else if (k == 9 && msk) {
        int lt = label[b * 128 + t];
        num += tr_s[lastlab][lt] + emis[((long)b * 128 + t) * 16 + lt];
        lastlab = lt;
      }
      __syncthreads();
      if (k < 9) { a = anew; al_s[bl][k] = a; }
      __syncthreads();
    }
    if (k == 9) num_s[bl] = num + endt[lastlab];
    __syncthreads();
    if (k == 0) {
      float mx = -1e30f;
#pragma unroll
      for (int j = 0; j < 9; ++j) mx = fmaxf(mx, al_s[bl][j] + endt[j]);
      float ss = 0.f;
#pragma unroll
      for (int j = 0; j < 9; ++j) ss += __expf(al_s[bl][j] + endt[j] - mx);
      red_s[bl] = (mx + __logf(ss)) - num_s[bl];
    }
    __syncthreads();
    if (tid == 0) {
      float s = 0.f;
      for (int i = 0; i < 16; ++i) s += red_s[i];
      atomicAdd(out, s);
    }
  } else {
    int vb = bid - 16;
    int b = vb * 16 + bl;
    float v = -1e30f;
    if (k < 9) v = startt[k] + emis[((long)b * 128) * 16 + k];
    al_s[bl][k] = v;
    __syncthreads();
    for (int t = 1; t < 128; ++t) {
      float vnew = v;
      if (k < 9) {
        float best = -1e30f; int bi = 0;
#pragma unroll
        for (int j = 0; j < 9; ++j) {
          float tot = al_s[bl][j] + tr_s[j][k];
          if (tot > best) { best = tot; bi = j; }
        }
        vnew = best + emis[((long)b * 128 + t) * 16 + k];
        bpl[(bl * 127 + (t - 1)) * 16 + k] = (unsigned char)bi;
      }
      __syncthreads();
      if (k < 9) { v = vnew; al_s[bl][k] = v; }
      __syncthreads();
    }
    if (tid < 16) {
      int bb = vb * 16 + tid;
      float best = -1e30f; int tag = 0;
#pragma unroll
      for (int j = 0; j < 9; ++j) {
        float vv = al_s[tid][j] + endt[j];
        if (vv > best) { best = vv; tag = j; }
      }
      out[1 + bb * 128 + 127] = (float)tag;
      for (int t = 127; t >= 1; --t) {
        tag = bpl[(tid * 127 + (t - 1)) * 16 + tag];
        out[1 + bb * 128 + t - 1] = (float)tag;
      }
    }
  }
}

__global__ void k_sent(float* out) { out[0] = -1.0e6f; }

// ---------- launch ----------
extern "C" void kernel_launch(void* const* d_in, const int* in_sizes, int n_in,
                              void* d_out, int out_size, void* d_ws, size_t ws_size,
                              hipStream_t stream) {
  const int* in_x    = (const int*)d_in[0];
  const int* label   = (const int*)d_in[1];
  const float* emb   = (const float*)d_in[2];
  const float* Wih_f = (const float*)d_in[3];
  const float* Whh_f = (const float*)d_in[4];
  const float* b_f   = (const float*)d_in[5];
  const float* Wih_b = (const float*)d_in[6];
  const float* Whh_b = (const float*)d_in[7];
  const float* b_b   = (const float*)d_in[8];
  const float* W_emit= (const float*)d_in[9];
  const float* b_emit= (const float*)d_in[10];
  const float* start_t=(const float*)d_in[11];
  const float* end_t = (const float*)d_in[12];
  const float* trans = (const float*)d_in[13];
  const float* h0f   = (const float*)d_in[14];
  const float* c0f   = (const float*)d_in[15];
  const float* h0b   = (const float*)d_in[16];
  const float* c0b   = (const float*)d_in[17];
  (void)in_sizes; (void)n_in; (void)out_size;

  auto align = [](size_t x) { return (x + 255) & ~(size_t)255; };
  size_t fixed = 0;
  fixed += align(32768L * 256 * 2);   // HF bf16
  fixed += align(32768L * 256 * 2);   // HB bf16
  fixed += align(30000L * 256 * 2);   // EBH
  fixed += align(2048L * 256 * 2);    // WIHH bf16
  fixed += align(16L * 512 * 2);      // WEH
  fixed += align(2048L * 256);        // WHH8 fp8
  fixed += align(32768L * 16 * 4);    // EMIS
  fixed += align(2L * 256 * 256 * 4); // CSTATE

  int S = 0;
  const int cands[4] = {128, 64, 32, 16};
  for (int ci = 0; ci < 4; ++ci) {
    size_t xb = align(1048576L * cands[ci]);
    if (xb + fixed <= ws_size) { S = cands[ci]; break; }
  }
  if (S == 0) { k_sent<<<1, 1, 0, stream>>>((float*)d_out); return; }
  int logS = __builtin_ctz(S);
  int NC = 128 / S;

  char* ws = (char*)d_ws;
  size_t o = 0;
  auto alloc = [&](size_t sz) { size_t r = o; o += (sz + 255) & ~(size_t)255; return r; };
  u16* xw    = (u16*)(ws + alloc(1048576L * S));
  u16* hf    = (u16*)(ws + alloc(32768L * 256 * 2));
  u16* hb    = (u16*)(ws + alloc(32768L * 256 * 2));
  u16* ebh   = (u16*)(ws + alloc(30000L * 256 * 2));
  u16* wihh  = (u16*)(ws + alloc(2048L * 256 * 2));
  u16* weh   = (u16*)(ws + alloc(16L * 512 * 2));
  char* whh8 = (char*)(ws + alloc(2048L * 256));
  float* emis= (float*)(ws + alloc(32768L * 16 * 4));
  float* cstate = (float*)(ws + alloc(2L * 256 * 256 * 4));

  k_prep<<<8020, 256, 0, stream>>>(emb, Wih_f, Wih_b, W_emit, ebh, wihh, weh);
  k_prep_whh<<<256, 256, 0, stream>>>(Whh_f, Whh_b, whh8);
  for (int c = 0; c < NC; ++c) {
    k_gemm_in<<<dim3(2 * S, 8, 2), 256, 0, stream>>>(in_x, ebh, wihh, b_f, b_b,
                                                     xw, c * S, S, logS);
    k_lstm<<<32, 512, 0, stream>>>(whh8, h0f, c0f, h0b, c0b, xw, hf, hb,
                                   cstate, c * S, S, c == 0 ? 1 : 0, c == NC - 1 ? 1 : 0);
  }
  k_emis<<<512, 256, 0, stream>>>(hf, hb, weh, b_emit, emis, (float*)d_out);
  k_tail<<<32, 256, 0, stream>>>(emis, in_x, label, start_t, end_t, trans, (float*)d_out);
}

// Round 11
// 386.941 us; speedup vs baseline: 1.9418x; 1.7330x over previous
//
#include <hip/hip_runtime.h>

typedef __attribute__((ext_vector_type(8))) short bf16x8;
typedef __attribute__((ext_vector_type(4))) float f32x4;
typedef __attribute__((ext_vector_type(4))) unsigned u32x4;
typedef unsigned short u16;

#define SENT 0xC1C1C1C1u

// ---------- helpers ----------
__device__ __forceinline__ u16 f2bf(float f) {
  union { float f; unsigned u; } v; v.f = f;
  unsigned r = v.u + 0x7fffu + ((v.u >> 16) & 1u);
  return (u16)(r >> 16);
}
__device__ __forceinline__ unsigned cvt_pk(float lo, float hi) {
  unsigned r;
  asm("v_cvt_pk_bf16_f32 %0, %1, %2" : "=v"(r) : "v"(lo), "v"(hi));
  return r;
}
__device__ __forceinline__ float sigm(float x) { return 1.f / (1.f + __expf(-x)); }
__device__ __forceinline__ float tanhf_(float x) { return 1.f - 2.f / (__expf(2.f * x) + 1.f); }

// ---------- K0: one-pass prep: emb -> fp8 eb8 | Wih f,b -> fp8 wih8 | W_emit -> bf16 weh ----------
__global__ __launch_bounds__(256) void k_prep(const float* __restrict__ emb,
    const float* __restrict__ wf, const float* __restrict__ wb, const float* __restrict__ we,
    char* __restrict__ eb8, char* __restrict__ wih8, u16* __restrict__ weh) {
  int i4 = (blockIdx.x * 256 + threadIdx.x) * 4;
  if (i4 < 8204288) {
    const float* src; char* dst; int o;
    if (i4 < 7680000) { src = emb + i4; dst = eb8; o = i4; }
    else { int off = i4 - 7680000;
           src = (off < 262144) ? (wf + off) : (wb + off - 262144);
           dst = wih8; o = off; }
    f32x4 v = *(const f32x4*)src;
    int r0 = __builtin_amdgcn_cvt_pk_fp8_f32(v[0], v[1], 0, false);
    r0 = __builtin_amdgcn_cvt_pk_fp8_f32(v[2], v[3], r0, true);
    *(int*)(dst + o) = r0;
  } else {
    int off = i4 - 8204288;          // 0..8191
    int r = off >> 9, k = off & 511;
    f32x4 v = (r < 9) ? *(const f32x4*)(we + r * 512 + k) : (f32x4){0.f, 0.f, 0.f, 0.f};
    *(unsigned*)(weh + off) = cvt_pk(v[0], v[1]);
    *(unsigned*)(weh + off + 2) = cvt_pk(v[2], v[3]);
  }
}

// ---------- K1: fused BiLSTM (input GEMM folded in), sentinel-dataflow cross-block sync ----------
// 256 blocks = 2 dir x 16 batch-slices x 8 j-slices; per block LDS: Whh slice bf16 (67.6K) +
// Wih slice fp8 (33.8K) + h stage (8.4K) + x stage fp8 (4.3K) + gate exchange (8.4K) = 122.6 KB.
// Each block computes its own Wih·x gate-columns (disjoint across j-slices -> no duplicate FLOP).
#define LW 264
__global__ __launch_bounds__(256) void k_lstm(
    const float* __restrict__ whh_f, const float* __restrict__ whh_b,
    const char* __restrict__ wih8, const char* __restrict__ eb8,
    const int* __restrict__ ix,
    const float* __restrict__ bf_, const float* __restrict__ bb_,
    const float* __restrict__ h0f, const float* __restrict__ c0f,
    const float* __restrict__ h0b, const float* __restrict__ c0b,
    u16* __restrict__ hf, u16* __restrict__ hb) {
  __shared__ u16 wlh[128 * LW];              // Whh slice bf16
  __shared__ char wli8[128 * 264];           // Wih slice fp8
  __shared__ u16 hst[16 * LW];               // h(t-1) stage bf16
  __shared__ __align__(16) char hsa8[16 * 272];  // x(t) stage fp8
  __shared__ float gl[16 * 132];             // gate exchange f32
  int bid = blockIdx.x;
  int js = (bid >> 3) & 7;
  int G = ((bid >> 6) << 3) | (bid & 7);
  int dir = G >> 4, bs = G & 15;
  const float* whh = dir ? whh_b : whh_f;
  u16* hout = dir ? hb : hf;
  int tid = threadIdx.x;
  for (int i = 0; i < 128; ++i) {
    int q = i >> 5, u = i & 31;
    int gate = q * 256 + js * 32 + u;
    wlh[i * LW + tid] = f2bf(whh[gate * 256 + tid]);
    wli8[i * 264 + tid] = wih8[(dir * 1024 + gate) * 256 + tid];
  }
  int b_l = tid >> 4, jj = tid & 15;
  int b_g = bs * 16 + b_l;
  int jg0 = js * 32 + jj * 2;
  // biases (replace the old xw prefetch)
  const float* bsrc = dir ? bb_ : bf_;
  float bI0 = bsrc[jg0],       bI1 = bsrc[jg0 + 1];
  float bF0 = bsrc[256 + jg0], bF1 = bsrc[257 + jg0];
  float bG0 = bsrc[512 + jg0], bG1 = bsrc[513 + jg0];
  float bO0 = bsrc[768 + jg0], bO1 = bsrc[769 + jg0];
  const float* c0 = dir ? c0b : c0f;
  float cv0 = c0[b_g * 256 + jg0];
  float cv1 = c0[b_g * 256 + jg0 + 1];
  int w = tid >> 6, l = tid & 63, la = l & 15, lk = (l >> 4) * 8;
  int srow = tid >> 4, scol = (tid & 15) * 16;
  const float* h0 = dir ? h0b : h0f;
  const int* ixrow = ix + (bs * 16 + srow) * 128;
  // prefetch x-row for step 0
  u32x4 aR;
  {
    int tA = dir ? 127 : 0;
    const char* ap = eb8 + (long)ixrow[tA] * 256 + scol;
    aR = *(const u32x4*)ap;
  }
  __syncthreads();
  for (int sl = 0; sl < 128; ++sl) {
    int t_io = dir ? 127 - sl : sl;
    // stage x(t) (prefetched last iteration)
    *(u32x4*)&hsa8[srow * 272 + scol] = aR;
    // stage h(t-1)
    u16* hd = &hst[srow * LW + scol];
    if (sl == 0) {
      const float* p = h0 + (bs * 16 + srow) * 256 + scol;
      f32x4 v0 = *(const f32x4*)p, v1 = *(const f32x4*)(p + 4);
      f32x4 v2 = *(const f32x4*)(p + 8), v3 = *(const f32x4*)(p + 12);
      u32x4 qa, qb;
      qa[0] = cvt_pk(v0[0], v0[1]); qa[1] = cvt_pk(v0[2], v0[3]);
      qa[2] = cvt_pk(v1[0], v1[1]); qa[3] = cvt_pk(v1[2], v1[3]);
      qb[0] = cvt_pk(v2[0], v2[1]); qb[1] = cvt_pk(v2[2], v2[3]);
      qb[2] = cvt_pk(v3[0], v3[1]); qb[3] = cvt_pk(v3[2], v3[3]);
      *(u32x4*)hd = qa; *((u32x4*)hd + 1) = qb;
    } else {
      int tp = dir ? t_io + 1 : t_io - 1;
      const u16* p = hout + ((long)(bs * 16 + srow) * 128 + tp) * 256 + scol;
      u32x4 r0, r1; int guard = 0; bool ok;
      do {
        asm volatile(
          "global_load_dwordx4 %0, %2, off sc0 sc1\n\t"
          "global_load_dwordx4 %1, %2, off offset:16 sc0 sc1\n\t"
          "s_waitcnt vmcnt(0)"
          : "=v"(r0), "=v"(r1) : "v"(p) : "memory");
        ok = (r0[0] != SENT) & (r0[1] != SENT) & (r0[2] != SENT) & (r0[3] != SENT)
           & (r1[0] != SENT) & (r1[1] != SENT) & (r1[2] != SENT) & (r1[3] != SENT);
      } while (__builtin_expect(!ok, 0) && ++guard < (1 << 22));
      *(u32x4*)hd = r0; *((u32x4*)hd + 1) = r1;
    }
    __syncthreads();
    // ---- MFMA: gates = Wih·x + Whh·h for this block's 2x16 gate rows ----
    f32x4 a0 = (f32x4){0.f, 0.f, 0.f, 0.f}, a1 = (f32x4){0.f, 0.f, 0.f, 0.f};
#pragma unroll
    for (int ks = 0; ks < 8; ++ks) {
      int k = ks * 32 + lk;
      long xv = *(const long*)&hsa8[la * 272 + k];
      bf16x8 hh = *(const bf16x8*)&hst[la * LW + k];
      int r0_ = w * 32 + la, r1_ = w * 32 + 16 + la;
      long wi0 = *(const long*)&wli8[r0_ * 264 + k];
      long wi1 = *(const long*)&wli8[r1_ * 264 + k];
      bf16x8 wh0 = *(const bf16x8*)&wlh[r0_ * LW + k];
      bf16x8 wh1 = *(const bf16x8*)&wlh[r1_ * LW + k];
      a0 = __builtin_amdgcn_mfma_f32_16x16x32_fp8_fp8(xv, wi0, a0, 0, 0, 0);
      a0 = __builtin_amdgcn_mfma_f32_16x16x32_bf16(hh, wh0, a0, 0, 0, 0);
      a1 = __builtin_amdgcn_mfma_f32_16x16x32_fp8_fp8(xv, wi1, a1, 0, 0, 0);
      a1 = __builtin_amdgcn_mfma_f32_16x16x32_bf16(hh, wh1, a1, 0, 0, 0);
    }
#pragma unroll
    for (int r = 0; r < 4; ++r) {
      gl[((l >> 4) * 4 + r) * 132 + w * 32 + la] = a0[r];
      gl[((l >> 4) * 4 + r) * 132 + w * 32 + 16 + la] = a1[r];
    }
    __syncthreads();
    float hv0, hv1;
    {
      int jl = jj * 2;
      float gi = gl[b_l * 132 + jl]      + bI0;
      float gf = gl[b_l * 132 + 32 + jl] + bF0;
      float gg = gl[b_l * 132 + 64 + jl] + bG0;
      float go = gl[b_l * 132 + 96 + jl] + bO0;
      float c = sigm(gf) * cv0 + sigm(gi) * tanhf_(gg);
      cv0 = c; hv0 = sigm(go) * tanhf_(c);
    }
    {
      int jl = jj * 2 + 1;
      float gi = gl[b_l * 132 + jl]      + bI1;
      float gf = gl[b_l * 132 + 32 + jl] + bF1;
      float gg = gl[b_l * 132 + 64 + jl] + bG1;
      float go = gl[b_l * 132 + 96 + jl] + bO1;
      float c = sigm(gf) * cv1 + sigm(gi) * tanhf_(gg);
      cv1 = c; hv1 = sigm(go) * tanhf_(c);
    }
    unsigned pk = cvt_pk(hv0, hv1);
    __hip_atomic_store((unsigned*)(hout + ((long)b_g * 128 + t_io) * 256 + jg0), pk,
                       __ATOMIC_RELAXED, __HIP_MEMORY_SCOPE_AGENT);
    // prefetch next step's x-row (completes during next poll)
    if (sl < 127) {
      int tN = dir ? 126 - sl : sl + 1;
      const char* ap = eb8 + (long)ixrow[tN] * 256 + scol;
      aR = *(const u32x4*)ap;
    }
  }
}

// ---------- K3: emission (also zero-inits out[0] for the tail's atomic loss sum) ----------
__global__ __launch_bounds__(256) void k_emis(const u16* __restrict__ hfb, const u16* __restrict__ hbb,
    const u16* __restrict__ weh, const float* __restrict__ bemit, float* __restrict__ emis,
    float* __restrict__ out) {
  if (blockIdx.x == 0 && threadIdx.x == 0) out[0] = 0.f;
  int w = threadIdx.x >> 6, l = threadIdx.x & 63;
  int la = l & 15, lk = (l >> 4) * 8;
  long m0 = (long)blockIdx.x * 64 + w * 16;
  long am = m0 + la;
  f32x4 acc = (f32x4){0.f, 0.f, 0.f, 0.f};
#pragma unroll
  for (int ks = 0; ks < 16; ++ks) {
    int k = ks * 32 + lk;
    const u16* src = (k < 256) ? (hfb + am * 256 + k) : (hbb + am * 256 + (k - 256));
    bf16x8 ah = *(const bf16x8*)src;
    bf16x8 bh = *(const bf16x8*)(weh + la * 512 + k);
    acc = __builtin_amdgcn_mfma_f32_16x16x32_bf16(ah, bh, acc, 0, 0, 0);
  }
  int kout = la;
  float bias = (kout < 9) ? bemit[kout] : 0.f;
  long mr = m0 + (l >> 4) * 4;
#pragma unroll
  for (int r = 0; r < 4; ++r)
    emis[(mr + r) * 16 + kout] = acc[r] + bias;
}

// ---------- K4: fused tail. Blocks 0-15: CRF -> atomicAdd loss. 16-31: Viterbi + backtrace. ----------
__global__ __launch_bounds__(256) void k_tail(const float* __restrict__ emis, const int* __restrict__ ixin,
    const int* __restrict__ label, const float* __restrict__ startt, const float* __restrict__ endt,
    const float* __restrict__ trans, float* __restrict__ out) {
  __shared__ float al_s[16][16];
  __shared__ float tr_s[9][16];
  __shared__ float num_s[16];
  __shared__ float red_s[16];
  __shared__ unsigned char bpl[16 * 127 * 16];
  int tid = threadIdx.x, bl = tid >> 4, k = tid & 15;
  int bid = blockIdx.x;
  if (bl < 9) tr_s[bl][k] = (k < 9) ? trans[bl * 9 + k] : 0.f;
  if (bid < 16) {
    int b = bid * 16 + bl;
    float a = 0.f, num = 0.f;
    int lastlab = 0;
    if (k < 9) a = startt[k] + emis[((long)b * 128) * 16 + k];
    al_s[bl][k] = a;
    if (k == 9) {
      int l0 = label[b * 128];
      num = startt[l0] + emis[((long)b * 128) * 16 + l0];
      lastlab = l0;
    }
    __syncthreads();
    for (int t = 1; t < 128; ++t) {
      bool msk = ixin[b * 128 + t] != 0;
      float anew = a;
      if (k < 9) {
        float mx = -1e30f;
#pragma unroll
        for (int j = 0; j < 9; ++j) mx = fmaxf(mx, al_s[bl][j] + tr_s[j][k]);
        float ss = 0.f;
#pragma unroll
        for (int j = 0; j < 9; ++j) ss += __expf(al_s[bl][j] + tr_s[j][k] - mx);
        anew = mx + __logf(ss) + emis[((long)b * 128 + t) * 16 + k];
        if (!msk) anew = a;
      } else if (k == 9 && msk) {
        int lt = label[b * 128 + t];
        num += tr_s[lastlab][lt] + emis[((long)b * 128 + t) * 16 + lt];
        lastlab = lt;
      }
      __syncthreads();
      if (k < 9) { a = anew; al_s[bl][k] = a; }
      __syncthreads();
    }
    if (k == 9) num_s[bl] = num + endt[lastlab];
    __syncthreads();
    if (k == 0) {
      float mx = -1e30f;
#pragma unroll
      for (int j = 0; j < 9; ++j) mx = fmaxf(mx, al_s[bl][j] + endt[j]);
      float ss = 0.f;
#pragma unroll
      for (int j = 0; j < 9; ++j) ss += __expf(al_s[bl][j] + endt[j] - mx);
      red_s[bl] = (mx + __logf(ss)) - num_s[bl];
    }
    __syncthreads();
    if (tid == 0) {
      float s = 0.f;
      for (int i = 0; i < 16; ++i) s += red_s[i];
      atomicAdd(out, s);
    }
  } else {
    int vb = bid - 16;
    int b = vb * 16 + bl;
    float v = -1e30f;
    if (k < 9) v = startt[k] + emis[((long)b * 128) * 16 + k];
    al_s[bl][k] = v;
    __syncthreads();
    for (int t = 1; t < 128; ++t) {
      float vnew = v;
      if (k < 9) {
        float best = -1e30f; int bi = 0;
#pragma unroll
        for (int j = 0; j < 9; ++j) {
          float tot = al_s[bl][j] + tr_s[j][k];
          if (tot > best) { best = tot; bi = j; }
        }
        vnew = best + emis[((long)b * 128 + t) * 16 + k];
        bpl[(bl * 127 + (t - 1)) * 16 + k] = (unsigned char)bi;
      }
      __syncthreads();
      if (k < 9) { v = vnew; al_s[bl][k] = v; }
      __syncthreads();
    }
    if (tid < 16) {
      int bb = vb * 16 + tid;
      float best = -1e30f; int tag = 0;
#pragma unroll
      for (int j = 0; j < 9; ++j) {
        float vv = al_s[tid][j] + endt[j];
        if (vv > best) { best = vv; tag = j; }
      }
      out[1 + bb * 128 + 127] = (float)tag;
      for (int t = 127; t >= 1; --t) {
        tag = bpl[(tid * 127 + (t - 1)) * 16 + tag];
        out[1 + bb * 128 + t - 1] = (float)tag;
      }
    }
  }
}

__global__ void k_sent(float* out) { out[0] = -1.0e6f; }

// ---------- launch ----------
extern "C" void kernel_launch(void* const* d_in, const int* in_sizes, int n_in,
                              void* d_out, int out_size, void* d_ws, size_t ws_size,
                              hipStream_t stream) {
  const int* in_x    = (const int*)d_in[0];
  const int* label   = (const int*)d_in[1];
  const float* emb   = (const float*)d_in[2];
  const float* Wih_f = (const float*)d_in[3];
  const float* Whh_f = (const float*)d_in[4];
  const float* b_f   = (const float*)d_in[5];
  const float* Wih_b = (const float*)d_in[6];
  const float* Whh_b = (const float*)d_in[7];
  const float* b_b   = (const float*)d_in[8];
  const float* W_emit= (const float*)d_in[9];
  const float* b_emit= (const float*)d_in[10];
  const float* start_t=(const float*)d_in[11];
  const float* end_t = (const float*)d_in[12];
  const float* trans = (const float*)d_in[13];
  const float* h0f   = (const float*)d_in[14];
  const float* c0f   = (const float*)d_in[15];
  const float* h0b   = (const float*)d_in[16];
  const float* c0b   = (const float*)d_in[17];
  (void)in_sizes; (void)n_in; (void)out_size;

  auto align = [](size_t x) { return (x + 255) & ~(size_t)255; };
  char* ws = (char*)d_ws;
  size_t o = 0;
  auto alloc = [&](size_t sz) { size_t r = o; o += (sz + 255) & ~(size_t)255; return r; };
  size_t need = align(32768L * 256 * 2) * 2 + align(30000L * 256) + align(2048L * 256)
              + align(16L * 512 * 2) + align(32768L * 16 * 4);
  if (need > ws_size) { k_sent<<<1, 1, 0, stream>>>((float*)d_out); return; }

  u16* hf    = (u16*)(ws + alloc(32768L * 256 * 2));
  u16* hb    = (u16*)(ws + alloc(32768L * 256 * 2));
  char* eb8  = (char*)(ws + alloc(30000L * 256));
  char* wih8 = (char*)(ws + alloc(2048L * 256));
  u16* weh   = (u16*)(ws + alloc(16L * 512 * 2));
  float* emis= (float*)(ws + alloc(32768L * 16 * 4));

  // sentinel-init h buffers (0xC1C1 bf16 == -24.1, impossible for tanh*sigm output);
  // re-poisoned every call so graph replays never see stale h as "ready".
  hipMemsetAsync(hf, 0xC1, 32768L * 256 * 2, stream);
  hipMemsetAsync(hb, 0xC1, 32768L * 256 * 2, stream);
  k_prep<<<8020, 256, 0, stream>>>(emb, Wih_f, Wih_b, W_emit, eb8, wih8, weh);
  k_lstm<<<256, 256, 0, stream>>>(Whh_f, Whh_b, wih8, eb8, in_x, b_f, b_b,
                                  h0f, c0f, h0b, c0b, hf, hb);
  k_emis<<<512, 256, 0, stream>>>(hf, hb, weh, b_emit, emis, (float*)d_out);
  k_tail<<<32, 256, 0, stream>>>(emis, in_x, label, start_t, end_t, trans, (float*)d_out);
}